// Round 6
// baseline (1274.697 us; speedup 1.0000x reference)
//
#include <hip/hip_runtime.h>
#include <stdint.h>

#define BB 16
#define CC 2048
#define DD 256
#define MM (BB*CC)

// Diagnostic repeat counts (idempotent kernels; amplifies dispatch dur_us
// above the ~310us harness-fill threshold so counters become visible).
#define REP_TRIG  16
#define REP_WCONV 16
#define REP_QKV    8
#define REP_ATTN   4

typedef __attribute__((ext_vector_type(4))) float f32x4;
typedef __attribute__((ext_vector_type(8))) short bf16x8;
typedef __attribute__((ext_vector_type(4))) short s16x4;

static __device__ __forceinline__ short f2bf(float f) {
  union { float f; uint32_t u; } v; v.f = f;
  uint32_t u = v.u;
  return (short)((u + 0x7FFFu + ((u >> 16) & 1u)) >> 16);
}

// async global->LDS, 16B per lane, dest = uniform base + lane*16
#define GLDS16(gp, lp) __builtin_amdgcn_global_load_lds(                      \
    (const __attribute__((address_space(1))) void*)(gp),                      \
    (__attribute__((address_space(3))) void*)(lp), 16, 0, 0)

// ---------------------------------------------------------------------------
// Kernel 1: cos/sin table (fp64 pow + mod-2pi, fast f32 trig).
// ---------------------------------------------------------------------------
__global__ __launch_bounds__(256) void k_trig(float2* __restrict__ cs) {
  #pragma unroll 1
  for (int rep = 0; rep < REP_TRIG; ++rep) {
    int id = blockIdx.x * 256 + threadIdx.x;     // CC*128 threads
    int pos = id >> 7, k = id & 127;
    double th = pow(10000.0, (1.0 - (double)k) * (1.0 / 128.0));
    double ang = (double)pos * th;
    const double TWO_PI = 6.283185307179586476925287;
    double red = ang - floor(ang * (1.0 / TWO_PI)) * TWO_PI;
    float fr = (float)red;
    cs[id] = make_float2(__cosf(fr), __sinf(fr));
  }
}

// ---------------------------------------------------------------------------
// Kernel 2: W{q,k,v} f32 -> bf16 in GLDS-linear order (16KB per-kc slices).
// ---------------------------------------------------------------------------
__global__ __launch_bounds__(256) void k_wconv(
    const float* __restrict__ Wq, const float* __restrict__ Wk,
    const float* __restrict__ Wv, short* __restrict__ wb) {
  #pragma unroll 1
  for (int rep = 0; rep < REP_WCONV; ++rep) {
    int gid = blockIdx.x * 256 + threadIdx.x;    // 49152 groups of 8B
    int mat = gid >> 14;
    int rem = gid & 16383;
    int kc = rem >> 11;
    int o  = (rem & 2047) * 8;
    int e  = o >> 6;
    int c4 = ((o & 63) ^ (((e >> 1) & 3) << 4)) >> 3;
    const float* W = (mat == 0) ? Wq : (mat == 1) ? Wk : Wv;
    f32x4 wv = *(const f32x4*)(W + (size_t)e * DD + kc * 32 + c4 * 4);
    s16x4 b4;
    b4[0] = f2bf(wv[0]); b4[1] = f2bf(wv[1]); b4[2] = f2bf(wv[2]); b4[3] = f2bf(wv[3]);
    *(s16x4*)((char*)wb + (size_t)gid * 8) = b4;
  }
}

// ---------------------------------------------------------------------------
// Kernel 3: fused QKV projection + RoPE; v written directly transposed.
// ---------------------------------------------------------------------------
__global__ __launch_bounds__(256, 2) void k_qkv(
    const float* __restrict__ x, const short* __restrict__ wb,
    const float* __restrict__ bq, const float* __restrict__ bk,
    const float* __restrict__ bv, const float2* __restrict__ cs,
    short* __restrict__ q_rot, short* __restrict__ k_rot,
    short* __restrict__ v_t)
{
  __shared__ char SM[32768 + 49152];   // xs 32KB | wsh 48KB
  short* xs = (short*)SM;
  char* wsh = SM + 32768;
  const int t = threadIdx.x;
  const int lane = t & 63, w = t >> 6;
  const int g = lane >> 4, li = lane & 15;
  const int m0 = blockIdx.x * 64;

  #pragma unroll 1
  for (int rep = 0; rep < REP_QKV; ++rep) {
    __syncthreads();                   // SM reuse across reps

    // stage x tile (f32 -> bf16), swizzled rows 512B
    #pragma unroll
    for (int i = 0; i < 16; ++i) {
      int chunk = i * 256 + t;
      int row = chunk >> 6, c4 = chunk & 63;
      f32x4 xv = *(const f32x4*)(x + (size_t)(m0 + row) * DD + c4 * 4);
      s16x4 b4;
      b4[0] = f2bf(xv[0]); b4[1] = f2bf(xv[1]); b4[2] = f2bf(xv[2]); b4[3] = f2bf(xv[3]);
      *(s16x4*)((char*)xs + row * 512 + ((c4 * 8) ^ ((row & 7) << 4))) = b4;
    }
    __syncthreads();

    f32x4 zero4 = {0.f, 0.f, 0.f, 0.f};
    f32x4 accQ[16], accK[16], accV[16];
    #pragma unroll
    for (int nt = 0; nt < 16; ++nt) { accQ[nt] = zero4; accK[nt] = zero4; accV[nt] = zero4; }

    for (int kc = 0; kc < 8; ++kc) {
      #pragma unroll
      for (int i = 0; i < 12; ++i) {
        int cc = i * 4 + w;
        const char* src = (const char*)wb + (size_t)(cc >> 4) * 131072 +
                          kc * 16384 + (cc & 15) * 1024 + lane * 16;
        GLDS16(src, wsh + cc * 1024);
      }
      asm volatile("s_waitcnt vmcnt(0)" ::: "memory");
      __builtin_amdgcn_sched_barrier(0);
      __builtin_amdgcn_s_barrier();

      const int arow = w * 16 + li;
      bf16x8 a = *(const bf16x8*)((char*)xs + arow * 512 +
                                  (((kc * 64) + g * 16) ^ ((arow & 7) << 4)));
      #pragma unroll
      for (int nt = 0; nt < 16; ++nt) {
        int e = nt * 16 + li;
        int off = e * 64 + ((g * 16) ^ (((e >> 1) & 3) << 4));
        bf16x8 fq = *(const bf16x8*)(wsh + off);
        bf16x8 fk = *(const bf16x8*)(wsh + 16384 + off);
        bf16x8 fv = *(const bf16x8*)(wsh + 32768 + off);
        accQ[nt] = __builtin_amdgcn_mfma_f32_16x16x32_bf16(a, fq, accQ[nt], 0, 0, 0);
        accK[nt] = __builtin_amdgcn_mfma_f32_16x16x32_bf16(a, fk, accK[nt], 0, 0, 0);
        accV[nt] = __builtin_amdgcn_mfma_f32_16x16x32_bf16(a, fv, accV[nt], 0, 0, 0);
      }
      __builtin_amdgcn_s_barrier();
    }

    // q,k epilogue: bias + RoPE
    #pragma unroll
    for (int nt = 0; nt < 16; ++nt) {
      int e = nt * 16 + li;
      float bQ = bq[e], bK = bk[e];
      #pragma unroll
      for (int r = 0; r < 4; ++r) {
        int m = m0 + w * 16 + g * 4 + r;
        float2 csv = cs[(size_t)(m & (CC - 1)) * 128 + (e >> 1)];
        float vq = accQ[nt][r] + bQ;
        float oq = __shfl_xor(vq, 1);
        vq = csv.x * vq + ((e & 1) ? csv.y * oq : -csv.y * oq);
        q_rot[(size_t)m * DD + e] = f2bf(vq * 0.0625f);
        float vk = accK[nt][r] + bK;
        float ok = __shfl_xor(vk, 1);
        vk = csv.x * vk + ((e & 1) ? csv.y * ok : -csv.y * ok);
        k_rot[(size_t)m * DD + e] = f2bf(vk);
      }
    }
    // v epilogue: LDS transpose -> coalesced stores
    __syncthreads();
    #pragma unroll
    for (int nt = 0; nt < 16; ++nt) {
      int e = nt * 16 + li;
      float bias = bv[e];
      #pragma unroll
      for (int r = 0; r < 4; ++r) {
        int cloc = w * 16 + g * 4 + r;
        *(short*)(SM + e * 144 + cloc * 2) = f2bf(accV[nt][r] + bias);
      }
    }
    __syncthreads();
    {
      const int bb = m0 >> 11, c0 = m0 & (CC - 1);
      #pragma unroll
      for (int it = 0; it < 8; ++it) {
        int chunk = it * 256 + t;
        int e = chunk >> 3, c8 = chunk & 7;
        int4 vv = *(const int4*)(SM + e * 144 + c8 * 16);
        *(int4*)(v_t + ((size_t)(bb * DD + e)) * CC + c0 + c8 * 8) = vv;
      }
    }
  }
}

// ---------------------------------------------------------------------------
// Kernel 4: causal flash attention (best-so-far config: 512 blocks x 128 thr,
// QBLK=64, KVBLK=32, dbuf + counted vmcnt, complement-paired dispatch).
// ---------------------------------------------------------------------------
__global__ __launch_bounds__(128, 2) void k_attn(
    const short* __restrict__ q_rot, const short* __restrict__ k_rot,
    const short* __restrict__ v_t, float* __restrict__ out)
{
  __shared__ short Ks[2][32 * DD];   // 2 x 16KB, rows 512B, swz (row&7)<<4
  __shared__ short Vs[2][DD * 32];   // 2 x 16KB, rows 64B,  swz (d&3)<<4
  __shared__ short Ps[2][32 * 40];   // per-wave P [32 q][32 kv + pad] 80B rows
  const int t = threadIdx.x;
  const int lane = t & 63, w = t >> 6;          // w: 0..1
  const int g = lane >> 4, li = lane & 15;

  const int p = blockIdx.x;
  const int xcd = p & 7, s = p >> 3;            // s: 0..63
  const int idx = (s < 32) ? (s >> 1) : ((s - 32) >> 1);
  const int qt = (s < 32) ? (31 - idx) : idx;   // heavy half first
  const int b = 2 * xcd + (s & 1);
  const int q0 = qt * 64;
  const int NT = 2 * qt + 2;                    // kv tiles of 32

  const short* kbase = k_rot + (size_t)b * CC * DD;
  const short* vbase = v_t + (size_t)b * DD * CC;

  // Q fragments: rows q0 + w*32 + rb*16 + li
  bf16x8 qf[2][8];
  #pragma unroll
  for (int rb = 0; rb < 2; ++rb) {
    const short* qb = q_rot + ((size_t)b * CC + q0 + w * 32 + rb * 16 + li) * DD;
    #pragma unroll
    for (int dc = 0; dc < 8; ++dc)
      qf[rb][dc] = *(const bf16x8*)(qb + dc * 32 + g * 8);
  }
  asm volatile("s_waitcnt vmcnt(0)" ::: "memory");
  __builtin_amdgcn_sched_barrier(0);

  f32x4 zero4 = {0.f, 0.f, 0.f, 0.f};

  auto STAGE = [&](int buf, int kt) {           // 16 GLDS16 per wave
    const int k0s = kt * 32;
    #pragma unroll
    for (int i = 0; i < 8; ++i) {               // K tile: 16 chunks of 1KB
      int c = i * 2 + w;
      int row = 2 * c + (lane >> 5);
      int cb = (lane & 31) * 16;
      const char* src = (const char*)(kbase + (size_t)(k0s + row) * DD) +
                        (cb ^ ((row & 7) << 4));
      GLDS16(src, (char*)(&Ks[buf][0]) + c * 1024);
    }
    #pragma unroll
    for (int i = 0; i < 8; ++i) {               // V tile: 16 chunks of 1KB
      int c = i * 2 + w;
      int d = 16 * c + (lane >> 2);
      int cb = ((lane & 3) * 16) ^ ((d & 3) << 4);
      const char* src = (const char*)(vbase + (size_t)d * CC + k0s) + cb;
      GLDS16(src, (char*)(&Vs[buf][0]) + c * 1024);
    }
  };

  #pragma unroll 1
  for (int rep = 0; rep < REP_ATTN; ++rep) {
    __syncthreads();                            // LDS reuse across reps

    f32x4 O[2][16];
    #pragma unroll
    for (int rb = 0; rb < 2; ++rb)
      #pragma unroll
      for (int i = 0; i < 16; ++i) O[rb][i] = zero4;
    float mrow[2][4], lrow[2][4];
    #pragma unroll
    for (int rb = 0; rb < 2; ++rb)
      #pragma unroll
      for (int r = 0; r < 4; ++r) { mrow[rb][r] = -__builtin_inff(); lrow[rb][r] = 0.f; }

    int cur = 0;
    STAGE(0, 0);
    for (int kt = 0; kt < NT; ++kt) {
      const int k0 = kt * 32;
      if (kt + 1 < NT) {
        STAGE(cur ^ 1, kt + 1);
        asm volatile("s_waitcnt vmcnt(16)" ::: "memory");
      } else {
        asm volatile("s_waitcnt vmcnt(0)" ::: "memory");
      }
      __builtin_amdgcn_sched_barrier(0);
      __builtin_amdgcn_s_barrier();

      // S = Q K^T
      f32x4 S[2][2];
      #pragma unroll
      for (int rb = 0; rb < 2; ++rb) { S[rb][0] = zero4; S[rb][1] = zero4; }
      __builtin_amdgcn_s_setprio(1);
      #pragma unroll
      for (int dc = 0; dc < 8; ++dc) {
        #pragma unroll
        for (int nt = 0; nt < 2; ++nt) {
          int krow = nt * 16 + li;
          bf16x8 kf = *(const bf16x8*)((char*)(&Ks[cur][0]) + krow * 512 +
                                       (((dc * 64) + g * 16) ^ ((krow & 7) << 4)));
          S[0][nt] = __builtin_amdgcn_mfma_f32_16x16x32_bf16(qf[0][dc], kf, S[0][nt], 0, 0, 0);
          S[1][nt] = __builtin_amdgcn_mfma_f32_16x16x32_bf16(qf[1][dc], kf, S[1][nt], 0, 0, 0);
        }
      }
      __builtin_amdgcn_s_setprio(0);

      if (kt >= NT - 2) {
        #pragma unroll
        for (int rb = 0; rb < 2; ++rb)
          #pragma unroll
          for (int nt = 0; nt < 2; ++nt)
            #pragma unroll
            for (int r = 0; r < 4; ++r)
              if ((k0 + nt * 16 + li) > (q0 + w * 32 + rb * 16 + g * 4 + r))
                S[rb][nt][r] = -__builtin_inff();
      }

      // online softmax with defer-max (THR=8)
      float mxr[2][4];
      #pragma unroll
      for (int rb = 0; rb < 2; ++rb)
        #pragma unroll
        for (int r = 0; r < 4; ++r) {
          float mx = fmaxf(S[rb][0][r], S[rb][1][r]);
          mx = fmaxf(mx, __shfl_xor(mx, 1));
          mx = fmaxf(mx, __shfl_xor(mx, 2));
          mx = fmaxf(mx, __shfl_xor(mx, 4));
          mx = fmaxf(mx, __shfl_xor(mx, 8));
          mxr[rb][r] = mx;
        }
      int need = 0;
      #pragma unroll
      for (int rb = 0; rb < 2; ++rb)
        #pragma unroll
        for (int r = 0; r < 4; ++r) need |= (mxr[rb][r] > mrow[rb][r] + 8.f) ? 1 : 0;
      if (__any(need)) {
        #pragma unroll
        for (int rb = 0; rb < 2; ++rb)
          #pragma unroll
          for (int r = 0; r < 4; ++r) {
            float mnew = fmaxf(mrow[rb][r], mxr[rb][r]);
            float al = __expf(mrow[rb][r] - mnew);
            mrow[rb][r] = mnew;
            lrow[rb][r] *= al;
            #pragma unroll
            for (int dt2 = 0; dt2 < 16; ++dt2) O[rb][dt2][r] *= al;
          }
      }
      #pragma unroll
      for (int rb = 0; rb < 2; ++rb)
        #pragma unroll
        for (int r = 0; r < 4; ++r) {
          float rsum = 0.f;
          #pragma unroll
          for (int nt = 0; nt < 2; ++nt) {
            float pv = __expf(S[rb][nt][r] - mrow[rb][r]);
            S[rb][nt][r] = pv;
            rsum += pv;
          }
          rsum += __shfl_xor(rsum, 1);
          rsum += __shfl_xor(rsum, 2);
          rsum += __shfl_xor(rsum, 4);
          rsum += __shfl_xor(rsum, 8);
          lrow[rb][r] += rsum;
        }

      // P (C-layout) -> per-wave LDS -> A-frags
      #pragma unroll
      for (int rb = 0; rb < 2; ++rb)
        #pragma unroll
        for (int nt = 0; nt < 2; ++nt)
          #pragma unroll
          for (int r = 0; r < 4; ++r) {
            int pr = rb * 16 + g * 4 + r;
            *(short*)((char*)(&Ps[w][0]) + pr * 80 + (nt * 16 + li) * 2) =
                f2bf(S[rb][nt][r]);
          }

      // O += P V
      __builtin_amdgcn_s_setprio(1);
      bf16x8 pf0 = *(const bf16x8*)((char*)(&Ps[w][0]) + li * 80 + g * 16);
      bf16x8 pf1 = *(const bf16x8*)((char*)(&Ps[w][0]) + (16 + li) * 80 + g * 16);
      #pragma unroll
      for (int dt2 = 0; dt2 < 16; ++dt2) {
        int vrow = dt2 * 16 + li;
        bf16x8 vf = *(const bf16x8*)((char*)(&Vs[cur][0]) + vrow * 64 +
                                     ((g * 16) ^ ((vrow & 3) << 4)));
        O[0][dt2] = __builtin_amdgcn_mfma_f32_16x16x32_bf16(pf0, vf, O[0][dt2], 0, 0, 0);
        O[1][dt2] = __builtin_amdgcn_mfma_f32_16x16x32_bf16(pf1, vf, O[1][dt2], 0, 0, 0);
      }
      __builtin_amdgcn_s_setprio(0);
      __builtin_amdgcn_s_barrier();
      cur ^= 1;
    } // kt

    // epilogue: normalize and store f32
    #pragma unroll
    for (int rb = 0; rb < 2; ++rb) {
      float invl[4];
      #pragma unroll
      for (int r = 0; r < 4; ++r) invl[r] = 1.f / lrow[rb][r];
      #pragma unroll
      for (int dt2 = 0; dt2 < 16; ++dt2)
        #pragma unroll
        for (int r = 0; r < 4; ++r) {
          int qr = q0 + w * 32 + rb * 16 + g * 4 + r;
          out[((size_t)b * CC + qr) * DD + dt2 * 16 + li] = O[rb][dt2][r] * invl[r];
        }
    }
  } // rep
}

// ---------------------------------------------------------------------------
extern "C" void kernel_launch(void* const* d_in, const int* in_sizes, int n_in,
                              void* d_out, int out_size, void* d_ws, size_t ws_size,
                              hipStream_t stream) {
  const float* x  = (const float*)d_in[0];
  const float* Wq = (const float*)d_in[1];
  const float* bq = (const float*)d_in[2];
  const float* Wk = (const float*)d_in[3];
  const float* bk = (const float*)d_in[4];
  const float* Wv = (const float*)d_in[5];
  const float* bv = (const float*)d_in[6];
  float* out = (float*)d_out;
  (void)in_sizes; (void)n_in; (void)out_size; (void)ws_size;

  // ws layout: cs 2MB | q_rot 16MB | k_rot 16MB | v_t 16MB | wb 384KB
  char* ws = (char*)d_ws;
  float2* cs   = (float2*)ws;
  short* q_rot = (short*)(ws + (2u << 20));
  short* k_rot = q_rot + (size_t)MM * DD;
  short* v_tr  = k_rot + (size_t)MM * DD;
  short* wb    = v_tr + (size_t)MM * DD;

  k_trig <<<1024, 256, 0, stream>>>(cs);
  k_wconv<<< 192, 256, 0, stream>>>(Wq, Wk, Wv, wb);
  k_qkv  <<< 512, 256, 0, stream>>>(x, wb, bq, bk, bv, cs, q_rot, k_rot, v_tr);
  k_attn <<< 512, 128, 0, stream>>>(q_rot, k_rot, v_tr, out);
}

// Round 7
// 212.728 us; speedup vs baseline: 5.9921x; 5.9921x over previous
//
#include <hip/hip_runtime.h>
#include <stdint.h>

#define BB 16
#define CC 2048
#define DD 256
#define MM (BB*CC)

typedef __attribute__((ext_vector_type(4))) float f32x4;
typedef __attribute__((ext_vector_type(8))) short bf16x8;
typedef __attribute__((ext_vector_type(4))) short s16x4;

static __device__ __forceinline__ short f2bf(float f) {
  union { float f; uint32_t u; } v; v.f = f;
  uint32_t u = v.u;
  return (short)((u + 0x7FFFu + ((u >> 16) & 1u)) >> 16);
}

// async global->LDS, 16B per lane, dest = uniform base + lane*16
#define GLDS16(gp, lp) __builtin_amdgcn_global_load_lds(                      \
    (const __attribute__((address_space(1))) void*)(gp),                      \
    (__attribute__((address_space(3))) void*)(lp), 16, 0, 0)

// ---------------------------------------------------------------------------
// Kernel 1: cos/sin table (fp64 pow + mod-2pi, fast f32 trig).
// ---------------------------------------------------------------------------
__global__ __launch_bounds__(256) void k_trig(float2* __restrict__ cs) {
  int id = blockIdx.x * 256 + threadIdx.x;     // CC*128 threads
  int pos = id >> 7, k = id & 127;
  double th = pow(10000.0, (1.0 - (double)k) * (1.0 / 128.0));
  double ang = (double)pos * th;
  const double TWO_PI = 6.283185307179586476925287;
  double red = ang - floor(ang * (1.0 / TWO_PI)) * TWO_PI;
  float fr = (float)red;
  cs[id] = make_float2(__cosf(fr), __sinf(fr));
}

// ---------------------------------------------------------------------------
// Kernel 2: W{q,k,v} f32 -> bf16 in GLDS-linear order (16KB per-kc slices).
// ---------------------------------------------------------------------------
__global__ __launch_bounds__(256) void k_wconv(
    const float* __restrict__ Wq, const float* __restrict__ Wk,
    const float* __restrict__ Wv, short* __restrict__ wb) {
  int gid = blockIdx.x * 256 + threadIdx.x;    // 49152 groups of 8B
  int mat = gid >> 14;
  int rem = gid & 16383;
  int kc = rem >> 11;
  int o  = (rem & 2047) * 8;
  int e  = o >> 6;
  int c4 = ((o & 63) ^ (((e >> 1) & 3) << 4)) >> 3;
  const float* W = (mat == 0) ? Wq : (mat == 1) ? Wk : Wv;
  f32x4 wv = *(const f32x4*)(W + (size_t)e * DD + kc * 32 + c4 * 4);
  s16x4 b4;
  b4[0] = f2bf(wv[0]); b4[1] = f2bf(wv[1]); b4[2] = f2bf(wv[2]); b4[3] = f2bf(wv[3]);
  *(s16x4*)((char*)wb + (size_t)gid * 8) = b4;
}

// ---------------------------------------------------------------------------
// Kernel 3: fused QKV projection + RoPE; v written directly transposed.
// ---------------------------------------------------------------------------
__global__ __launch_bounds__(256, 2) void k_qkv(
    const float* __restrict__ x, const short* __restrict__ wb,
    const float* __restrict__ bq, const float* __restrict__ bk,
    const float* __restrict__ bv, const float2* __restrict__ cs,
    short* __restrict__ q_rot, short* __restrict__ k_rot,
    short* __restrict__ v_t)
{
  __shared__ char SM[32768 + 49152];   // xs 32KB | wsh 48KB
  short* xs = (short*)SM;
  char* wsh = SM + 32768;
  const int t = threadIdx.x;
  const int lane = t & 63, w = t >> 6;
  const int g = lane >> 4, li = lane & 15;
  const int m0 = blockIdx.x * 64;

  // stage x tile (f32 -> bf16), swizzled rows 512B
  #pragma unroll
  for (int i = 0; i < 16; ++i) {
    int chunk = i * 256 + t;
    int row = chunk >> 6, c4 = chunk & 63;
    f32x4 xv = *(const f32x4*)(x + (size_t)(m0 + row) * DD + c4 * 4);
    s16x4 b4;
    b4[0] = f2bf(xv[0]); b4[1] = f2bf(xv[1]); b4[2] = f2bf(xv[2]); b4[3] = f2bf(xv[3]);
    *(s16x4*)((char*)xs + row * 512 + ((c4 * 8) ^ ((row & 7) << 4))) = b4;
  }
  __syncthreads();

  f32x4 zero4 = {0.f, 0.f, 0.f, 0.f};
  f32x4 accQ[16], accK[16], accV[16];
  #pragma unroll
  for (int nt = 0; nt < 16; ++nt) { accQ[nt] = zero4; accK[nt] = zero4; accV[nt] = zero4; }

  for (int kc = 0; kc < 8; ++kc) {
    #pragma unroll
    for (int i = 0; i < 12; ++i) {
      int cc = i * 4 + w;
      const char* src = (const char*)wb + (size_t)(cc >> 4) * 131072 +
                        kc * 16384 + (cc & 15) * 1024 + lane * 16;
      GLDS16(src, wsh + cc * 1024);
    }
    asm volatile("s_waitcnt vmcnt(0)" ::: "memory");
    __builtin_amdgcn_sched_barrier(0);
    __builtin_amdgcn_s_barrier();

    const int arow = w * 16 + li;
    bf16x8 a = *(const bf16x8*)((char*)xs + arow * 512 +
                                (((kc * 64) + g * 16) ^ ((arow & 7) << 4)));
    #pragma unroll
    for (int nt = 0; nt < 16; ++nt) {
      int e = nt * 16 + li;
      int off = e * 64 + ((g * 16) ^ (((e >> 1) & 3) << 4));
      bf16x8 fq = *(const bf16x8*)(wsh + off);
      bf16x8 fk = *(const bf16x8*)(wsh + 16384 + off);
      bf16x8 fv = *(const bf16x8*)(wsh + 32768 + off);
      accQ[nt] = __builtin_amdgcn_mfma_f32_16x16x32_bf16(a, fq, accQ[nt], 0, 0, 0);
      accK[nt] = __builtin_amdgcn_mfma_f32_16x16x32_bf16(a, fk, accK[nt], 0, 0, 0);
      accV[nt] = __builtin_amdgcn_mfma_f32_16x16x32_bf16(a, fv, accV[nt], 0, 0, 0);
    }
    __builtin_amdgcn_s_barrier();
  }

  // q,k epilogue: bias + RoPE
  #pragma unroll
  for (int nt = 0; nt < 16; ++nt) {
    int e = nt * 16 + li;
    float bQ = bq[e], bK = bk[e];
    #pragma unroll
    for (int r = 0; r < 4; ++r) {
      int m = m0 + w * 16 + g * 4 + r;
      float2 csv = cs[(size_t)(m & (CC - 1)) * 128 + (e >> 1)];
      float vq = accQ[nt][r] + bQ;
      float oq = __shfl_xor(vq, 1);
      vq = csv.x * vq + ((e & 1) ? csv.y * oq : -csv.y * oq);
      q_rot[(size_t)m * DD + e] = f2bf(vq * 0.0625f);
      float vk = accK[nt][r] + bK;
      float ok = __shfl_xor(vk, 1);
      vk = csv.x * vk + ((e & 1) ? csv.y * ok : -csv.y * ok);
      k_rot[(size_t)m * DD + e] = f2bf(vk);
    }
  }
  // v epilogue: LDS transpose -> coalesced stores
  __syncthreads();
  #pragma unroll
  for (int nt = 0; nt < 16; ++nt) {
    int e = nt * 16 + li;
    float bias = bv[e];
    #pragma unroll
    for (int r = 0; r < 4; ++r) {
      int cloc = w * 16 + g * 4 + r;
      *(short*)(SM + e * 144 + cloc * 2) = f2bf(accV[nt][r] + bias);
    }
  }
  __syncthreads();
  {
    const int bb = m0 >> 11, c0 = m0 & (CC - 1);
    #pragma unroll
    for (int it = 0; it < 8; ++it) {
      int chunk = it * 256 + t;
      int e = chunk >> 3, c8 = chunk & 7;
      int4 vv = *(const int4*)(SM + e * 144 + c8 * 16);
      *(int4*)(v_t + ((size_t)(bb * DD + e)) * CC + c0 + c8 * 8) = vv;
    }
  }
}

// ---------------------------------------------------------------------------
// Kernel 4: causal flash attention. 1024 blocks x 128 thr, QBLK=32
// (16 rows/wave), KVBLK=32. ALL blocks co-resident: 4 blocks/CU = 8 waves/CU
// = 2/SIMD; CU c hosts qt {j, 63-j, 16+j, 47-j} of one batch -> 130 iters/CU
// exactly. K: LDS double-buffer via GLDS16 + counted vmcnt. V: L2-direct
// register fragments issued at iter top (latency hidden under QK+softmax);
// each 64B V line fully consumed by one instruction.
// ---------------------------------------------------------------------------
__global__ __launch_bounds__(128, 2) void k_attn(
    const short* __restrict__ q_rot, const short* __restrict__ k_rot,
    const short* __restrict__ v_t, float* __restrict__ out)
{
  __shared__ short Ks[2][32 * DD];   // 2 x 16KB, rows 512B, swz (row&7)<<4
  __shared__ char  Ps[2][16 * 80];   // per-wave P [16 q][32 kv] pitch 80B
  const int t = threadIdx.x;
  const int lane = t & 63, w = t >> 6;          // 2 waves
  const int g = lane >> 4, li = lane & 15;

  const int p = blockIdx.x;                     // 0..1023
  const int b = p & 15;
  const int j = p >> 4;                         // 0..63
  const int g4 = j >> 4, r4 = j & 15;
  const int qt = (g4 == 0) ? r4 : (g4 == 1) ? (63 - r4)
               : (g4 == 2) ? (16 + r4) : (47 - r4);
  const int q0 = qt * 32;
  const int NT = qt + 1;                        // kv tiles of 32

  const short* kbase = k_rot + (size_t)b * CC * DD;
  const short* vbase = v_t  + (size_t)b * DD * CC;

  // Q fragments: rows q0 + w*16 + li
  const short* qb = q_rot + ((size_t)b * CC + q0 + w * 16 + li) * DD;
  bf16x8 qf[8];
  #pragma unroll
  for (int dc = 0; dc < 8; ++dc)
    qf[dc] = *(const bf16x8*)(qb + dc * 32 + g * 8);

  f32x4 zero4 = {0.f, 0.f, 0.f, 0.f};
  f32x4 O[16];
  #pragma unroll
  for (int i = 0; i < 16; ++i) O[i] = zero4;
  float mrow[4], lrow[4];
  #pragma unroll
  for (int r = 0; r < 4; ++r) { mrow[r] = -__builtin_inff(); lrow[r] = 0.f; }

  auto STAGE = [&](int buf, int kt) {           // 8 GLDS16 per wave (16 chunks)
    const int k0s = kt * 32;
    #pragma unroll
    for (int i = 0; i < 8; ++i) {
      int c = i * 2 + w;
      int row = 2 * c + (lane >> 5);
      int cb = ((lane & 31) * 16) ^ ((row & 7) << 4);
      const char* src = (const char*)(kbase + (size_t)(k0s + row) * DD) + cb;
      GLDS16(src, (char*)(&Ks[buf][0]) + c * 1024);
    }
  };

  char* Pb = &Ps[w][0];
  int cur = 0;
  STAGE(0, 0);
  for (int kt = 0; kt < NT; ++kt) {
    const int k0 = kt * 32;

    // V fragments for this tile, L2-direct (consumed after softmax)
    bf16x8 vf[16];
    #pragma unroll
    for (int dt2 = 0; dt2 < 16; ++dt2)
      vf[dt2] = *(const bf16x8*)(vbase + (size_t)(dt2 * 16 + li) * CC + k0 + g * 8);

    if (kt + 1 < NT) {
      STAGE(cur ^ 1, kt + 1);
      asm volatile("s_waitcnt vmcnt(24)" ::: "memory");  // K(cur) landed
    } else {
      asm volatile("s_waitcnt vmcnt(16)" ::: "memory");  // only V16 may remain
    }
    __builtin_amdgcn_sched_barrier(0);
    __builtin_amdgcn_s_barrier();

    // S = Q K^T (scale folded into q)
    f32x4 S[2];
    S[0] = zero4; S[1] = zero4;
    __builtin_amdgcn_s_setprio(1);
    #pragma unroll
    for (int dc = 0; dc < 8; ++dc) {
      #pragma unroll
      for (int nt = 0; nt < 2; ++nt) {
        int krow = nt * 16 + li;
        bf16x8 kf = *(const bf16x8*)((char*)(&Ks[cur][0]) + krow * 512 +
                                     (((dc * 64) + g * 16) ^ ((krow & 7) << 4)));
        S[nt] = __builtin_amdgcn_mfma_f32_16x16x32_bf16(qf[dc], kf, S[nt], 0, 0, 0);
      }
    }
    __builtin_amdgcn_s_setprio(0);

    // causal mask on the diagonal tile only (local indices: k0 == q0 there)
    if (kt == NT - 1) {
      #pragma unroll
      for (int nt = 0; nt < 2; ++nt)
        #pragma unroll
        for (int r = 0; r < 4; ++r)
          if ((nt * 16 + li) > (w * 16 + g * 4 + r))
            S[nt][r] = -__builtin_inff();
    }

    // online softmax with defer-max (THR=8)
    float mxr[4];
    #pragma unroll
    for (int r = 0; r < 4; ++r) {
      float mx = fmaxf(S[0][r], S[1][r]);
      mx = fmaxf(mx, __shfl_xor(mx, 1));
      mx = fmaxf(mx, __shfl_xor(mx, 2));
      mx = fmaxf(mx, __shfl_xor(mx, 4));
      mx = fmaxf(mx, __shfl_xor(mx, 8));
      mxr[r] = mx;
    }
    int need = 0;
    #pragma unroll
    for (int r = 0; r < 4; ++r) need |= (mxr[r] > mrow[r] + 8.f) ? 1 : 0;
    if (__any(need)) {
      #pragma unroll
      for (int r = 0; r < 4; ++r) {
        float mnew = fmaxf(mrow[r], mxr[r]);
        float al = __expf(mrow[r] - mnew);
        mrow[r] = mnew;
        lrow[r] *= al;
        #pragma unroll
        for (int dt2 = 0; dt2 < 16; ++dt2) O[dt2][r] *= al;
      }
    }
    #pragma unroll
    for (int r = 0; r < 4; ++r) {
      float rsum = 0.f;
      #pragma unroll
      for (int nt = 0; nt < 2; ++nt) {
        float pv = __expf(S[nt][r] - mrow[r]);
        S[nt][r] = pv;
        rsum += pv;
      }
      rsum += __shfl_xor(rsum, 1);
      rsum += __shfl_xor(rsum, 2);
      rsum += __shfl_xor(rsum, 4);
      rsum += __shfl_xor(rsum, 8);
      lrow[r] += rsum;
    }

    // P (C-layout) -> per-wave LDS (pitch 80 -> conflict-free read) -> A-frag
    #pragma unroll
    for (int nt = 0; nt < 2; ++nt)
      #pragma unroll
      for (int r = 0; r < 4; ++r)
        *(short*)(Pb + (g * 4 + r) * 80 + (nt * 16 + li) * 2) = f2bf(S[nt][r]);

    bf16x8 pf = *(const bf16x8*)(Pb + li * 80 + g * 16);

    // O += P V (V from registers)
    __builtin_amdgcn_s_setprio(1);
    #pragma unroll
    for (int dt2 = 0; dt2 < 16; ++dt2)
      O[dt2] = __builtin_amdgcn_mfma_f32_16x16x32_bf16(pf, vf[dt2], O[dt2], 0, 0, 0);
    __builtin_amdgcn_s_setprio(0);

    __builtin_amdgcn_s_barrier();               // readers done before restage
    cur ^= 1;
  } // kt

  // epilogue: normalize and store f32
  float invl[4];
  #pragma unroll
  for (int r = 0; r < 4; ++r) invl[r] = 1.f / lrow[r];
  #pragma unroll
  for (int dt2 = 0; dt2 < 16; ++dt2)
    #pragma unroll
    for (int r = 0; r < 4; ++r) {
      int qr = q0 + w * 16 + g * 4 + r;
      out[((size_t)b * CC + qr) * DD + dt2 * 16 + li] = O[dt2][r] * invl[r];
    }
}

// ---------------------------------------------------------------------------
extern "C" void kernel_launch(void* const* d_in, const int* in_sizes, int n_in,
                              void* d_out, int out_size, void* d_ws, size_t ws_size,
                              hipStream_t stream) {
  const float* x  = (const float*)d_in[0];
  const float* Wq = (const float*)d_in[1];
  const float* bq = (const float*)d_in[2];
  const float* Wk = (const float*)d_in[3];
  const float* bk = (const float*)d_in[4];
  const float* Wv = (const float*)d_in[5];
  const float* bv = (const float*)d_in[6];
  float* out = (float*)d_out;
  (void)in_sizes; (void)n_in; (void)out_size; (void)ws_size;

  // ws layout: cs 2MB | q_rot 16MB | k_rot 16MB | v_t 16MB | wb 384KB
  char* ws = (char*)d_ws;
  float2* cs   = (float2*)ws;
  short* q_rot = (short*)(ws + (2u << 20));
  short* k_rot = q_rot + (size_t)MM * DD;
  short* v_tr  = k_rot + (size_t)MM * DD;
  short* wb    = v_tr + (size_t)MM * DD;

  k_trig <<<1024, 256, 0, stream>>>(cs);
  k_wconv<<< 192, 256, 0, stream>>>(Wq, Wk, Wv, wb);
  k_qkv  <<< 512, 256, 0, stream>>>(x, wb, bq, bk, bv, cs, q_rot, k_rot, v_tr);
  k_attn <<<1024, 128, 0, stream>>>(q_rot, k_rot, v_tr, out);
}

// Round 8
// 130.696 us; speedup vs baseline: 9.7532x; 1.6277x over previous
//
#include <hip/hip_runtime.h>
#include <stdint.h>

#define BB 16
#define CC 2048
#define DD 256
#define MM (BB*CC)

typedef __attribute__((ext_vector_type(4))) float f32x4;
typedef __attribute__((ext_vector_type(8))) short bf16x8;
typedef __attribute__((ext_vector_type(4))) short s16x4;

static __device__ __forceinline__ short f2bf(float f) {
  union { float f; uint32_t u; } v; v.f = f;
  uint32_t u = v.u;
  return (short)((u + 0x7FFFu + ((u >> 16) & 1u)) >> 16);
}

// async global->LDS, 16B per lane, dest = uniform base + lane*16
#define GLDS16(gp, lp) __builtin_amdgcn_global_load_lds(                      \
    (const __attribute__((address_space(1))) void*)(gp),                      \
    (__attribute__((address_space(3))) void*)(lp), 16, 0, 0)

// DPP row_ror reduction step over the 16-lane group (ror n)
#define DPP_ROR_F(x, n) __uint_as_float(__builtin_amdgcn_update_dpp(          \
    0, (int)__float_as_uint(x), 0x120 + (n), 0xF, 0xF, false))

// ---------------------------------------------------------------------------
// Kernel 1: cos/sin table (fp64 pow + mod-2pi, fast f32 trig).
// ---------------------------------------------------------------------------
__global__ __launch_bounds__(256) void k_trig(float2* __restrict__ cs) {
  int id = blockIdx.x * 256 + threadIdx.x;     // CC*128 threads
  int pos = id >> 7, k = id & 127;
  double th = pow(10000.0, (1.0 - (double)k) * (1.0 / 128.0));
  double ang = (double)pos * th;
  const double TWO_PI = 6.283185307179586476925287;
  double red = ang - floor(ang * (1.0 / TWO_PI)) * TWO_PI;
  float fr = (float)red;
  cs[id] = make_float2(__cosf(fr), __sinf(fr));
}

// ---------------------------------------------------------------------------
// Kernel 2: W{q,k,v} f32 -> bf16 in GLDS-linear order (16KB per-kc slices).
// ---------------------------------------------------------------------------
__global__ __launch_bounds__(256) void k_wconv(
    const float* __restrict__ Wq, const float* __restrict__ Wk,
    const float* __restrict__ Wv, short* __restrict__ wb) {
  int gid = blockIdx.x * 256 + threadIdx.x;    // 49152 groups of 8B
  int mat = gid >> 14;
  int rem = gid & 16383;
  int kc = rem >> 11;
  int o  = (rem & 2047) * 8;
  int e  = o >> 6;
  int c4 = ((o & 63) ^ (((e >> 1) & 3) << 4)) >> 3;
  const float* W = (mat == 0) ? Wq : (mat == 1) ? Wk : Wv;
  f32x4 wv = *(const f32x4*)(W + (size_t)e * DD + kc * 32 + c4 * 4);
  s16x4 b4;
  b4[0] = f2bf(wv[0]); b4[1] = f2bf(wv[1]); b4[2] = f2bf(wv[2]); b4[3] = f2bf(wv[3]);
  *(s16x4*)((char*)wb + (size_t)gid * 8) = b4;
}

// ---------------------------------------------------------------------------
// Kernel 3: fused QKV projection + RoPE; v written directly transposed.
// ---------------------------------------------------------------------------
__global__ __launch_bounds__(256, 2) void k_qkv(
    const float* __restrict__ x, const short* __restrict__ wb,
    const float* __restrict__ bq, const float* __restrict__ bk,
    const float* __restrict__ bv, const float2* __restrict__ cs,
    short* __restrict__ q_rot, short* __restrict__ k_rot,
    short* __restrict__ v_t)
{
  __shared__ char SM[32768 + 49152];   // xs 32KB | wsh 48KB
  short* xs = (short*)SM;
  char* wsh = SM + 32768;
  const int t = threadIdx.x;
  const int lane = t & 63, w = t >> 6;
  const int g = lane >> 4, li = lane & 15;
  const int m0 = blockIdx.x * 64;

  // stage x tile (f32 -> bf16), swizzled rows 512B
  #pragma unroll
  for (int i = 0; i < 16; ++i) {
    int chunk = i * 256 + t;
    int row = chunk >> 6, c4 = chunk & 63;
    f32x4 xv = *(const f32x4*)(x + (size_t)(m0 + row) * DD + c4 * 4);
    s16x4 b4;
    b4[0] = f2bf(xv[0]); b4[1] = f2bf(xv[1]); b4[2] = f2bf(xv[2]); b4[3] = f2bf(xv[3]);
    *(s16x4*)((char*)xs + row * 512 + ((c4 * 8) ^ ((row & 7) << 4))) = b4;
  }
  __syncthreads();

  f32x4 zero4 = {0.f, 0.f, 0.f, 0.f};
  f32x4 accQ[16], accK[16], accV[16];
  #pragma unroll
  for (int nt = 0; nt < 16; ++nt) { accQ[nt] = zero4; accK[nt] = zero4; accV[nt] = zero4; }

  for (int kc = 0; kc < 8; ++kc) {
    #pragma unroll
    for (int i = 0; i < 12; ++i) {
      int cc = i * 4 + w;
      const char* src = (const char*)wb + (size_t)(cc >> 4) * 131072 +
                        kc * 16384 + (cc & 15) * 1024 + lane * 16;
      GLDS16(src, wsh + cc * 1024);
    }
    asm volatile("s_waitcnt vmcnt(0)" ::: "memory");
    __builtin_amdgcn_sched_barrier(0);
    __builtin_amdgcn_s_barrier();

    const int arow = w * 16 + li;
    bf16x8 a = *(const bf16x8*)((char*)xs + arow * 512 +
                                (((kc * 64) + g * 16) ^ ((arow & 7) << 4)));
    #pragma unroll
    for (int nt = 0; nt < 16; ++nt) {
      int e = nt * 16 + li;
      int off = e * 64 + ((g * 16) ^ (((e >> 1) & 3) << 4));
      bf16x8 fq = *(const bf16x8*)(wsh + off);
      bf16x8 fk = *(const bf16x8*)(wsh + 16384 + off);
      bf16x8 fv = *(const bf16x8*)(wsh + 32768 + off);
      accQ[nt] = __builtin_amdgcn_mfma_f32_16x16x32_bf16(a, fq, accQ[nt], 0, 0, 0);
      accK[nt] = __builtin_amdgcn_mfma_f32_16x16x32_bf16(a, fk, accK[nt], 0, 0, 0);
      accV[nt] = __builtin_amdgcn_mfma_f32_16x16x32_bf16(a, fv, accV[nt], 0, 0, 0);
    }
    __builtin_amdgcn_s_barrier();
  }

  // q,k epilogue: bias + RoPE
  #pragma unroll
  for (int nt = 0; nt < 16; ++nt) {
    int e = nt * 16 + li;
    float bQ = bq[e], bK = bk[e];
    #pragma unroll
    for (int r = 0; r < 4; ++r) {
      int m = m0 + w * 16 + g * 4 + r;
      float2 csv = cs[(size_t)(m & (CC - 1)) * 128 + (e >> 1)];
      float vq = accQ[nt][r] + bQ;
      float oq = __shfl_xor(vq, 1);
      vq = csv.x * vq + ((e & 1) ? csv.y * oq : -csv.y * oq);
      q_rot[(size_t)m * DD + e] = f2bf(vq * 0.0625f);
      float vk = accK[nt][r] + bK;
      float ok = __shfl_xor(vk, 1);
      vk = csv.x * vk + ((e & 1) ? csv.y * ok : -csv.y * ok);
      k_rot[(size_t)m * DD + e] = f2bf(vk);
    }
  }
  // v epilogue: LDS transpose -> coalesced stores
  __syncthreads();
  #pragma unroll
  for (int nt = 0; nt < 16; ++nt) {
    int e = nt * 16 + li;
    float bias = bv[e];
    #pragma unroll
    for (int r = 0; r < 4; ++r) {
      int cloc = w * 16 + g * 4 + r;
      *(short*)(SM + e * 144 + cloc * 2) = f2bf(accV[nt][r] + bias);
    }
  }
  __syncthreads();
  {
    const int bb = m0 >> 11, c0 = m0 & (CC - 1);
    #pragma unroll
    for (int it = 0; it < 8; ++it) {
      int chunk = it * 256 + t;
      int e = chunk >> 3, c8 = chunk & 7;
      int4 vv = *(const int4*)(SM + e * 144 + c8 * 16);
      *(int4*)(v_t + ((size_t)(bb * DD + e)) * CC + c0 + c8 * 8) = vv;
    }
  }
}

// ---------------------------------------------------------------------------
// Kernel 4: causal flash attention. 256 blocks x 512 thr = 1 block/CU,
// 8 waves (2/SIMD). Each block: complementary q-tile pair {j, 31-j} (64 rows
// each) sequentially -> exactly 33 group-iters per block (no tail). Waves
// split into 2 kv-groups of 4 (equal halves); per-group dbuf K+V in LDS via
// GLDS16 + counted vmcnt(8); ONE K/V copy per CU per tile (L2 traffic /6).
// DPP row_ror softmax reductions; LDS merge of the 2 groups per tile.
// ---------------------------------------------------------------------------
__global__ __launch_bounds__(512, 2) void k_attn(
    const short* __restrict__ q_rot, const short* __restrict__ k_rot,
    const short* __restrict__ v_t, float* __restrict__ out)
{
  // LDS: KV [0,128K): group g buf b at (g*2+b)*32768 {K 16KB | V 16KB}
  //      U  [64K, 64K+66560)  (merge, reuses group-1 KV space + a bit)
  //      P  [132608, +8*1280) ; ML [142848, +512)
  __shared__ char SM[143360];
  const int t = threadIdx.x;
  const int lane = t & 63, w = t >> 6;          // 8 waves
  const int wg = w & 3, gq = w >> 2;            // wave-in-group, kv-group
  const int g = lane >> 4, li = lane & 15;

  const int p = blockIdx.x;                     // 256 blocks, 1/CU
  const int b = p & 15;                         // batch -> XCD p%8 fixed
  const int j = p >> 4;                         // 0..15 pair index

  const short* kbase = k_rot + (size_t)b * CC * DD;
  const short* vbase = v_t  + (size_t)b * DD * CC;

  float* U  = (float*)(SM + 65536);             // [64][260] f32
  float* ML = (float*)(SM + 142848);            // [64][2]
  char* Pb = SM + 132608 + w * 1280;            // [16 q][40 sh] pitch 80B

  f32x4 zero4 = {0.f, 0.f, 0.f, 0.f};

  for (int tt = 0; tt < 2; ++tt) {
    const int qt = tt ? (31 - j) : j;           // pair sums to 33 group-iters
    const int q0 = qt * 64;
    const int NTg = qt + 1;                     // kv tiles of 32 per group
    const int kvoff = gq * 32 * NTg;            // group kv start

    // Q fragments: rows q0 + wg*16 + li
    const short* qb = q_rot + ((size_t)b * CC + q0 + wg * 16 + li) * DD;
    bf16x8 qf[8];
    #pragma unroll
    for (int dc = 0; dc < 8; ++dc)
      qf[dc] = *(const bf16x8*)(qb + dc * 32 + g * 8);

    f32x4 O[16];
    #pragma unroll
    for (int i = 0; i < 16; ++i) O[i] = zero4;
    float mrow[4], lrow[4];
    #pragma unroll
    for (int r = 0; r < 4; ++r) { mrow[r] = -__builtin_inff(); lrow[r] = 0.f; }

    auto STAGE = [&](int buf, int kt) {         // 8 GLDS16 per wave
      const int k0s = kvoff + kt * 32;
      char* dst = SM + (size_t)(gq * 2 + buf) * 32768;
      #pragma unroll
      for (int i = 0; i < 4; ++i) {             // K tile: 16 x 1KB chunks
        int c = i * 4 + wg;
        int row = 2 * c + (lane >> 5);
        int cb = ((lane & 31) * 16) ^ ((row & 7) << 4);
        const char* src = (const char*)(kbase + (size_t)(k0s + row) * DD) + cb;
        GLDS16(src, dst + c * 1024);
      }
      #pragma unroll
      for (int i = 0; i < 4; ++i) {             // V tile: 16 x 1KB chunks, linear
        int c = i * 4 + wg;
        int d = 16 * c + (lane >> 2);
        const char* src = (const char*)(vbase + (size_t)d * CC + k0s) +
                          (lane & 3) * 16;
        GLDS16(src, dst + 16384 + c * 1024);
      }
    };

    int cur = 0;
    STAGE(0, 0);
    for (int kt = 0; kt < NTg; ++kt) {
      const int k0 = kvoff + kt * 32;
      if (kt + 1 < NTg) {
        STAGE(cur ^ 1, kt + 1);
        asm volatile("s_waitcnt vmcnt(8)" ::: "memory");   // current tile landed
      } else {
        asm volatile("s_waitcnt vmcnt(0)" ::: "memory");
      }
      __builtin_amdgcn_sched_barrier(0);
      __builtin_amdgcn_s_barrier();

      const char* Kb = SM + (size_t)(gq * 2 + cur) * 32768;
      const char* Vb = Kb + 16384;

      // S = Q K^T (scale folded into q)
      f32x4 S[2];
      S[0] = zero4; S[1] = zero4;
      __builtin_amdgcn_s_setprio(1);
      #pragma unroll
      for (int dc = 0; dc < 8; ++dc) {
        #pragma unroll
        for (int nt = 0; nt < 2; ++nt) {
          int krow = nt * 16 + li;
          bf16x8 kf = *(const bf16x8*)(Kb + krow * 512 +
                                       (((dc * 64) + g * 16) ^ ((krow & 7) << 4)));
          S[nt] = __builtin_amdgcn_mfma_f32_16x16x32_bf16(qf[dc], kf, S[nt], 0, 0, 0);
        }
      }
      __builtin_amdgcn_s_setprio(0);

      // causal mask (finite sentinel); uniform cheap test
      if (k0 + 31 > q0) {
        #pragma unroll
        for (int nt = 0; nt < 2; ++nt)
          #pragma unroll
          for (int r = 0; r < 4; ++r)
            if ((k0 + nt * 16 + li) > (q0 + wg * 16 + g * 4 + r))
              S[nt][r] = -1.0e30f;
      }

      // online softmax, DPP row_ror reductions, defer-max (THR=8)
      float mxr[4];
      #pragma unroll
      for (int r = 0; r < 4; ++r) {
        float mx = fmaxf(S[0][r], S[1][r]);
        mx = fmaxf(mx, DPP_ROR_F(mx, 8));
        mx = fmaxf(mx, DPP_ROR_F(mx, 4));
        mx = fmaxf(mx, DPP_ROR_F(mx, 2));
        mx = fmaxf(mx, DPP_ROR_F(mx, 1));
        mxr[r] = mx;
      }
      int need = 0;
      #pragma unroll
      for (int r = 0; r < 4; ++r) need |= (mxr[r] > mrow[r] + 8.f) ? 1 : 0;
      if (__any(need)) {
        #pragma unroll
        for (int r = 0; r < 4; ++r) {
          float mnew = fmaxf(mrow[r], mxr[r]);
          float al = __expf(mrow[r] - mnew);
          mrow[r] = mnew;
          lrow[r] *= al;
          #pragma unroll
          for (int dt2 = 0; dt2 < 16; ++dt2) O[dt2][r] *= al;
        }
      }
      #pragma unroll
      for (int r = 0; r < 4; ++r) {
        float rsum = 0.f;
        #pragma unroll
        for (int nt = 0; nt < 2; ++nt) {
          float pv = __expf(S[nt][r] - mrow[r]);
          S[nt][r] = pv;
          rsum += pv;
        }
        rsum += DPP_ROR_F(rsum, 8);
        rsum += DPP_ROR_F(rsum, 4);
        rsum += DPP_ROR_F(rsum, 2);
        rsum += DPP_ROR_F(rsum, 1);
        lrow[r] += rsum;
      }

      // P (C-layout) -> per-wave LDS (pitch 80) -> A-frag
      #pragma unroll
      for (int nt = 0; nt < 2; ++nt)
        #pragma unroll
        for (int r = 0; r < 4; ++r)
          *(short*)(Pb + (g * 4 + r) * 80 + (nt * 16 + li) * 2) = f2bf(S[nt][r]);

      bf16x8 pf = *(const bf16x8*)(Pb + li * 80 + g * 16);

      // O += P V (V rows 64B, naturally conflict-free)
      __builtin_amdgcn_s_setprio(1);
      #pragma unroll
      for (int dt2 = 0; dt2 < 16; ++dt2) {
        bf16x8 vf = *(const bf16x8*)(Vb + (dt2 * 16 + li) * 64 + g * 16);
        O[dt2] = __builtin_amdgcn_mfma_f32_16x16x32_bf16(pf, vf, O[dt2], 0, 0, 0);
      }
      __builtin_amdgcn_s_setprio(0);

      __builtin_amdgcn_s_barrier();             // readers done before restage
      cur ^= 1;
    } // kt

    // ---- merge the two groups through LDS, normalize, store ----
    __syncthreads();
    if (gq == 1) {
      #pragma unroll
      for (int r = 0; r < 4; ++r) {
        int row = wg * 16 + g * 4 + r;
        if (li == 0) { ML[row * 2] = mrow[r]; ML[row * 2 + 1] = lrow[r]; }
        #pragma unroll
        for (int dt2 = 0; dt2 < 16; ++dt2)
          U[row * 260 + dt2 * 16 + li] = O[dt2][r];
      }
    }
    __syncthreads();
    if (gq == 0) {
      float eA[4], eB[4], invl[4];
      #pragma unroll
      for (int r = 0; r < 4; ++r) {
        int row = wg * 16 + g * 4 + r;
        float mB = ML[row * 2], lB = ML[row * 2 + 1];
        float m = fmaxf(mrow[r], mB);
        eA[r] = __expf(mrow[r] - m);
        eB[r] = __expf(mB - m);
        invl[r] = 1.f / (lrow[r] * eA[r] + lB * eB[r]);
      }
      #pragma unroll
      for (int dt2 = 0; dt2 < 16; ++dt2)
        #pragma unroll
        for (int r = 0; r < 4; ++r) {
          int row = wg * 16 + g * 4 + r;
          float uB = U[row * 260 + dt2 * 16 + li];
          out[((size_t)b * CC + q0 + row) * DD + dt2 * 16 + li] =
              (O[dt2][r] * eA[r] + uB * eB[r]) * invl[r];
        }
    }
    __syncthreads();                            // U region reused by next tile
  } // tt
}

// ---------------------------------------------------------------------------
extern "C" void kernel_launch(void* const* d_in, const int* in_sizes, int n_in,
                              void* d_out, int out_size, void* d_ws, size_t ws_size,
                              hipStream_t stream) {
  const float* x  = (const float*)d_in[0];
  const float* Wq = (const float*)d_in[1];
  const float* bq = (const float*)d_in[2];
  const float* Wk = (const float*)d_in[3];
  const float* bk = (const float*)d_in[4];
  const float* Wv = (const float*)d_in[5];
  const float* bv = (const float*)d_in[6];
  float* out = (float*)d_out;
  (void)in_sizes; (void)n_in; (void)out_size; (void)ws_size;

  // ws layout: cs 2MB | q_rot 16MB | k_rot 16MB | v_t 16MB | wb 384KB
  char* ws = (char*)d_ws;
  float2* cs   = (float2*)ws;
  short* q_rot = (short*)(ws + (2u << 20));
  short* k_rot = q_rot + (size_t)MM * DD;
  short* v_tr  = k_rot + (size_t)MM * DD;
  short* wb    = v_tr + (size_t)MM * DD;

  k_trig <<<1024, 256, 0, stream>>>(cs);
  k_wconv<<< 192, 256, 0, stream>>>(Wq, Wk, Wv, wb);
  k_qkv  <<< 512, 256, 0, stream>>>(x, wb, bq, bk, bv, cs, q_rot, k_rot, v_tr);
  k_attn <<< 256, 512, 0, stream>>>(q_rot, k_rot, v_tr, out);
}